// Round 3
// baseline (765.479 us; speedup 1.0000x reference)
//
#include <hip/hip_runtime.h>
#include <hip/hip_bf16.h>

#define NN   100000
#define HIDD 128

typedef __attribute__((ext_vector_type(8))) short bf16x8;
typedef __attribute__((ext_vector_type(4))) float f32x4;

// RNE fp32 -> bf16 bits
__device__ __forceinline__ short bf16_rne(float v) {
    unsigned u = __float_as_uint(v);
    unsigned r = (u + 0x7fffu + ((u >> 16) & 1u)) >> 16;
    return (short)r;
}
__device__ __forceinline__ float bf16_to_f32(short b) {
    return __uint_as_float(((unsigned)(unsigned short)b) << 16);
}

// ---------------------------------------------------------------------------
// CSR build
// ---------------------------------------------------------------------------
__global__ void count_kernel(const int* __restrict__ edges, int n_edges,
                             int* __restrict__ cnt) {
    int e = blockIdx.x * blockDim.x + threadIdx.x;
    if (e >= n_edges) return;
    unsigned s = (unsigned)edges[e];
    unsigned d = (unsigned)edges[n_edges + e];
    if (s < NN && d < NN) atomicAdd(&cnt[d], 1);
}

__global__ __launch_bounds__(256)
void scan_blocks(const int* __restrict__ cnt, int* __restrict__ partial,
                 int* __restrict__ bsums, int n) {
    __shared__ int lds[256];
    int t = threadIdx.x;
    int base = blockIdx.x * 1024 + t * 4;
    int v0 = 0, v1 = 0, v2 = 0, v3 = 0;
    if (base + 3 < n) {
        int4 v = *(const int4*)&cnt[base];
        v0 = v.x; v1 = v.y; v2 = v.z; v3 = v.w;
    } else {
        if (base + 0 < n) v0 = cnt[base + 0];
        if (base + 1 < n) v1 = cnt[base + 1];
        if (base + 2 < n) v2 = cnt[base + 2];
    }
    lds[t] = v0 + v1 + v2 + v3;
    __syncthreads();
    for (int off = 1; off < 256; off <<= 1) {
        int u = (t >= off) ? lds[t - off] : 0;
        __syncthreads();
        lds[t] += u;
        __syncthreads();
    }
    int excl = (t == 0) ? 0 : lds[t - 1];
    int i0 = excl + v0, i1 = i0 + v1, i2 = i1 + v2, i3 = i2 + v3;
    if (base + 0 < n) partial[base + 0] = i0;
    if (base + 1 < n) partial[base + 1] = i1;
    if (base + 2 < n) partial[base + 2] = i2;
    if (base + 3 < n) partial[base + 3] = i3;
    if (t == 255) bsums[blockIdx.x] = lds[255];
}

__global__ void scan_bsums(int* __restrict__ bsums, int nb) {
    __shared__ int lds[128];
    int t = threadIdx.x;
    lds[t] = (t < nb) ? bsums[t] : 0;
    __syncthreads();
    for (int off = 1; off < 128; off <<= 1) {
        int u = (t >= off) ? lds[t - off] : 0;
        __syncthreads();
        lds[t] += u;
        __syncthreads();
    }
    if (t < nb) bsums[t] = lds[t];
}

__global__ void finalize_rowptr(const int* __restrict__ partial,
                                const int* __restrict__ bsums,
                                int* __restrict__ row_ptr, int n) {
    int i = blockIdx.x * blockDim.x + threadIdx.x;
    if (i < n) {
        int b = i >> 10;
        int off = (b > 0) ? bsums[b - 1] : 0;
        row_ptr[i + 1] = partial[i] + off;
    }
    if (i == 0) row_ptr[0] = 0;
}

__global__ void fill_kernel(const int* __restrict__ edges, int n_edges,
                            const int* __restrict__ row_ptr,
                            int* __restrict__ cursor, int* __restrict__ col_src) {
    int e = blockIdx.x * blockDim.x + threadIdx.x;
    if (e >= n_edges) return;
    unsigned s = (unsigned)edges[e];
    unsigned d = (unsigned)edges[n_edges + e];
    if (s < NN && d < NN) {
        int pos = atomicAdd(&cursor[d], 1);
        col_src[row_ptr[d] + pos] = (int)s;
    }
}

// ---------------------------------------------------------------------------
// Pull-mode mean aggregation (fp32 canonical activations)
// ---------------------------------------------------------------------------
__global__ void aggregate128(const float* __restrict__ h,
                             const int* __restrict__ row_ptr,
                             const int* __restrict__ col_src,
                             float* __restrict__ aggr, int n_nodes) {
    int node = (int)((blockIdx.x * (size_t)blockDim.x + threadIdx.x) >> 6);
    int lane = threadIdx.x & 63;
    if (node >= n_nodes) return;
    int beg = row_ptr[node], end = row_ptr[node + 1];
    float ax = 0.f, ay = 0.f;
    int j = beg;
    for (; j + 4 <= end; j += 4) {
        int s0 = col_src[j], s1 = col_src[j + 1];
        int s2 = col_src[j + 2], s3 = col_src[j + 3];
        float2 v0 = *(const float2*)&h[(size_t)s0 * HIDD + lane * 2];
        float2 v1 = *(const float2*)&h[(size_t)s1 * HIDD + lane * 2];
        float2 v2 = *(const float2*)&h[(size_t)s2 * HIDD + lane * 2];
        float2 v3 = *(const float2*)&h[(size_t)s3 * HIDD + lane * 2];
        ax += (v0.x + v1.x) + (v2.x + v3.x);
        ay += (v0.y + v1.y) + (v2.y + v3.y);
    }
    for (; j < end; ++j) {
        int s = col_src[j];
        float2 v = *(const float2*)&h[(size_t)s * HIDD + lane * 2];
        ax += v.x; ay += v.y;
    }
    float inv = (end > beg) ? 1.0f / (float)(end - beg) : 0.0f;
    float2 o; o.x = ax * inv; o.y = ay * inv;
    *(float2*)&aggr[(size_t)node * HIDD + lane * 2] = o;
}

__global__ void aggregate32(const float* __restrict__ x,
                            const int* __restrict__ row_ptr,
                            const int* __restrict__ col_src,
                            float* __restrict__ aggr, int n_nodes) {
    int node = (int)((blockIdx.x * (size_t)blockDim.x + threadIdx.x) >> 5);
    int lane = threadIdx.x & 31;
    if (node >= n_nodes) return;
    int beg = row_ptr[node], end = row_ptr[node + 1];
    float a = 0.f;
    int j = beg;
    for (; j + 4 <= end; j += 4) {
        int s0 = col_src[j], s1 = col_src[j + 1];
        int s2 = col_src[j + 2], s3 = col_src[j + 3];
        float u0 = x[(size_t)s0 * 32 + lane];
        float u1 = x[(size_t)s1 * 32 + lane];
        float u2 = x[(size_t)s2 * 32 + lane];
        float u3 = x[(size_t)s3 * 32 + lane];
        a += (u0 + u1) + (u2 + u3);
    }
    for (; j < end; ++j) a += x[(size_t)col_src[j] * 32 + lane];
    float inv = (end > beg) ? 1.0f / (float)(end - beg) : 0.0f;
    aggr[(size_t)node * 32 + lane] = a * inv;
}

// ---------------------------------------------------------------------------
// Weight pre-split: fp32 -> (hi, lo) bf16 planes, all 6 conv matrices.
// Segment offsets (elements): W1l 0, W1r 4096, W2l 8192, W2r 24576,
//                             W3l 40960, W3r 57344, total 73728.
// ---------------------------------------------------------------------------
__global__ void split_weights(const float* __restrict__ W1l, const float* __restrict__ W1r,
                              const float* __restrict__ W2l, const float* __restrict__ W2r,
                              const float* __restrict__ W3l, const float* __restrict__ W3r,
                              short* __restrict__ whi, short* __restrict__ wlo) {
    int i = blockIdx.x * blockDim.x + threadIdx.x;
    if (i >= 73728) return;
    const float* src; int off;
    if (i < 4096)       { src = W1l; off = 0; }
    else if (i < 8192)  { src = W1r; off = 4096; }
    else if (i < 24576) { src = W2l; off = 8192; }
    else if (i < 40960) { src = W2r; off = 24576; }
    else if (i < 57344) { src = W3l; off = 40960; }
    else                { src = W3r; off = 57344; }
    float v = src[i - off];
    short h = bf16_rne(v);
    float l = v - bf16_to_f32(h);
    whi[i] = h;
    wlo[i] = bf16_rne(l);
}

// ---------------------------------------------------------------------------
// MFMA dual GEMM, split-bf16 precision:
//   out[n][o] = maybe_relu( sum_k inA[n][k]*WA[o][k] + inB[n][k]*WB[o][k] + bias[o] )
// A (fp32, canonical) split to hi/lo in-register; W pre-split planes.
// Block = 256 thr = 4 waves; tile 32 rows x 128 cols; wave: 16 rows x 64 cols
// (4 col-tiles of 16). Per k-chunk(32) per col-tile: Ahi*Whi + Ahi*Wlo + Alo*Whi.
// Fragment layouts (mfma_f32_16x16x32_bf16):
//   A: row=lane&15, k=(lane>>4)*8+e   B: col=lane&15, k=(lane>>4)*8+e
//   D: col=lane&15, row=(lane>>4)*4+reg     [m89-verified]
// MEAN: column sums (+bias*rows) accumulated into gsum instead of storing out.
// NN multiple of 32 -> no row tail.
// ---------------------------------------------------------------------------
template <int KA, bool RELU, bool MEAN>
__global__ __launch_bounds__(256)
void gemm_mfma(const float* __restrict__ inA, const float* __restrict__ inB,
               const short* __restrict__ WAhi, const short* __restrict__ WAlo,
               const short* __restrict__ WBhi, const short* __restrict__ WBlo,
               const float* __restrict__ bias,
               float* __restrict__ out, float* __restrict__ gsum) {
    __shared__ float gl[128];
    const int t = threadIdx.x;
    const int wave = t >> 6, lane = t & 63;
    const int lrow = lane & 15;
    const int lk8  = (lane >> 4) * 8;
    const int n0 = blockIdx.x * 32 + (wave >> 1) * 16;
    const int o0 = (wave & 1) * 64;

    if (MEAN) {
        if (t < 128) gl[t] = 0.f;
        __syncthreads();
    }

    f32x4 acc[4];
#pragma unroll
    for (int c = 0; c < 4; ++c) acc[c] = (f32x4){0.f, 0.f, 0.f, 0.f};

    for (int op = 0; op < 2; ++op) {
        const float* __restrict__ in  = op ? inB : inA;
        const short* __restrict__ Whi = op ? WBhi : WAhi;
        const short* __restrict__ Wlo = op ? WBlo : WAlo;
#pragma unroll
        for (int k0 = 0; k0 < KA; k0 += 32) {
            const float* ap = &in[(size_t)(n0 + lrow) * KA + k0 + lk8];
            float4 a0 = *(const float4*)ap;
            float4 a1 = *(const float4*)(ap + 4);
            float av[8] = {a0.x, a0.y, a0.z, a0.w, a1.x, a1.y, a1.z, a1.w};
            bf16x8 ahi, alo;
#pragma unroll
            for (int e = 0; e < 8; ++e) {
                float v = av[e];
                short h = bf16_rne(v);
                ahi[e] = h;
                alo[e] = bf16_rne(v - bf16_to_f32(h));
            }
#pragma unroll
            for (int ct = 0; ct < 4; ++ct) {
                size_t wbase = (size_t)(o0 + ct * 16 + lrow) * KA + k0 + lk8;
                bf16x8 wh = *(const bf16x8*)&Whi[wbase];
                bf16x8 wl = *(const bf16x8*)&Wlo[wbase];
                acc[ct] = __builtin_amdgcn_mfma_f32_16x16x32_bf16(ahi, wh, acc[ct], 0, 0, 0);
                acc[ct] = __builtin_amdgcn_mfma_f32_16x16x32_bf16(ahi, wl, acc[ct], 0, 0, 0);
                acc[ct] = __builtin_amdgcn_mfma_f32_16x16x32_bf16(alo, wh, acc[ct], 0, 0, 0);
            }
        }
    }

    if (!MEAN) {
        const int rg = (lane >> 4) * 4;  // row group base within 16-row tile
#pragma unroll
        for (int ct = 0; ct < 4; ++ct) {
            int o = o0 + ct * 16 + lrow;
            float b = bias[o];
#pragma unroll
            for (int r = 0; r < 4; ++r) {
                float v = acc[ct][r] + b;
                if (RELU) v = fmaxf(v, 0.f);
                out[(size_t)(n0 + rg + r) * HIDD + o] = v;
            }
        }
    } else {
#pragma unroll
        for (int ct = 0; ct < 4; ++ct) {
            float s = acc[ct][0] + acc[ct][1] + acc[ct][2] + acc[ct][3];
            s += __shfl_xor(s, 16);
            s += __shfl_xor(s, 32);
            if (lane < 16) atomicAdd(&gl[o0 + ct * 16 + lane], s);
        }
        __syncthreads();
        if (t < 128) atomicAdd(&gsum[t], gl[t] + bias[t] * 32.0f);
    }
}

// ---------------------------------------------------------------------------
// Heads: g = gsum/N; logits = relu(g@Pw1.T+Pb1)@Pw2.T+Pb2; value likewise.
// ---------------------------------------------------------------------------
__global__ void heads_kernel(const float* __restrict__ gsum,
                             const float* __restrict__ Pw1, const float* __restrict__ Pb1,
                             const float* __restrict__ Pw2, const float* __restrict__ Pb2,
                             const float* __restrict__ Vw1, const float* __restrict__ Vb1,
                             const float* __restrict__ Vw2, const float* __restrict__ Vb2,
                             float* __restrict__ out, float inv_n) {
    __shared__ float g[128], a1[128], v1[128];
    int t = threadIdx.x;
    if (t < 128) g[t] = gsum[t] * inv_n;
    __syncthreads();
    if (t < 128) {
        float s = Pb1[t];
        for (int f = 0; f < 128; ++f) s = fmaf(Pw1[t * 128 + f], g[f], s);
        a1[t] = fmaxf(s, 0.f);
    } else {
        int o = t - 128;
        float s = Vb1[o];
        for (int f = 0; f < 128; ++f) s = fmaf(Vw1[o * 128 + f], g[f], s);
        v1[o] = fmaxf(s, 0.f);
    }
    __syncthreads();
    if (t < 6) {
        float s = Pb2[t];
        for (int f = 0; f < 128; ++f) s = fmaf(Pw2[t * 128 + f], a1[f], s);
        out[t] = s;
    }
    if (t == 6) {
        float s = Vb2[0];
        for (int f = 0; f < 128; ++f) s = fmaf(Vw2[f], v1[f], s);
        out[6] = s;
    }
}

// ---------------------------------------------------------------------------
extern "C" void kernel_launch(void* const* d_in, const int* in_sizes, int n_in,
                              void* d_out, int out_size, void* d_ws, size_t ws_size,
                              hipStream_t stream) {
    const float* x    = (const float*)d_in[0];
    const int*   edges = (const int*)d_in[1];
    const float* W1l = (const float*)d_in[2];
    const float* b1  = (const float*)d_in[3];
    const float* W1r = (const float*)d_in[4];
    const float* W2l = (const float*)d_in[5];
    const float* b2  = (const float*)d_in[6];
    const float* W2r = (const float*)d_in[7];
    const float* W3l = (const float*)d_in[8];
    const float* b3  = (const float*)d_in[9];
    const float* W3r = (const float*)d_in[10];
    const float* Pw1 = (const float*)d_in[11];
    const float* Pb1 = (const float*)d_in[12];
    const float* Pw2 = (const float*)d_in[13];
    const float* Pb2 = (const float*)d_in[14];
    const float* Vw1 = (const float*)d_in[15];
    const float* Vb1 = (const float*)d_in[16];
    const float* Vw2 = (const float*)d_in[17];
    const float* Vb2 = (const float*)d_in[18];
    float* outp = (float*)d_out;

    const int E = in_sizes[1] / 2;

    // ---- workspace layout (4-byte element offsets) ----
    // [cnt N][cursor N][gsum 128f][bsums 128i][row_ptr N+1 pad]
    // [col_src E][whi 73728 s16][wlo 73728 s16][aggr N*128][hA N*128][hB N*128]
    int*   ws_i = (int*)d_ws;
    float* ws_f = (float*)d_ws;
    size_t o_cnt    = 0;
    size_t o_cursor = NN;
    size_t o_gsum   = 2 * (size_t)NN;
    size_t o_bsums  = 2 * (size_t)NN + 128;
    size_t o_rowptr = 2 * (size_t)NN + 256;
    size_t o_col    = o_rowptr + ((NN + 1 + 63) / 64) * 64;
    size_t o_whi    = ((o_col + (size_t)E + 63) / 64) * 64;   // 73728 shorts = 36864 ints
    size_t o_wlo    = o_whi + 36864;
    size_t o_aggr   = o_wlo + 36864;
    size_t o_hA     = o_aggr + (size_t)NN * HIDD;
    size_t o_hB     = o_hA + (size_t)NN * HIDD;

    int*   cnt     = ws_i + o_cnt;
    int*   cursor  = ws_i + o_cursor;
    float* gsum    = ws_f + o_gsum;
    int*   bsums   = ws_i + o_bsums;
    int*   row_ptr = ws_i + o_rowptr;
    int*   col_src = ws_i + o_col;
    short* whi     = (short*)(ws_i + o_whi);
    short* wlo     = (short*)(ws_i + o_wlo);
    float* aggr    = ws_f + o_aggr;
    float* hA      = ws_f + o_hA;
    float* hB      = ws_f + o_hB;

    // bf16 hi/lo weight plane segment offsets (elements)
    short* W1l_hi = whi + 0;     short* W1l_lo = wlo + 0;
    short* W1r_hi = whi + 4096;  short* W1r_lo = wlo + 4096;
    short* W2l_hi = whi + 8192;  short* W2l_lo = wlo + 8192;
    short* W2r_hi = whi + 24576; short* W2r_lo = wlo + 24576;
    short* W3l_hi = whi + 40960; short* W3l_lo = wlo + 40960;
    short* W3r_hi = whi + 57344; short* W3r_lo = wlo + 57344;

    // zero cnt, cursor, gsum in one shot
    hipMemsetAsync(d_ws, 0, (2 * (size_t)NN + 128) * sizeof(int), stream);

    const int TB = 256;
    dim3 blk(TB);
    dim3 grid_e((E + TB - 1) / TB);
    dim3 grid_n64(((size_t)NN * 64 + TB - 1) / TB);
    dim3 grid_n32(((size_t)NN * 32 + TB - 1) / TB);
    dim3 grid_g(NN / 32);                    // 3125 blocks, exact

    // Weight split (independent of CSR chain)
    split_weights<<<(73728 + TB - 1) / TB, blk, 0, stream>>>(
        W1l, W1r, W2l, W2r, W3l, W3r, whi, wlo);

    // CSR build (reused by all 3 layers)
    count_kernel<<<grid_e, blk, 0, stream>>>(edges, E, cnt);
    const int nb_scan = (NN + 1023) / 1024;
    scan_blocks<<<nb_scan, blk, 0, stream>>>(cnt, cnt /*alias ok*/, bsums, NN);
    scan_bsums<<<1, 128, 0, stream>>>(bsums, nb_scan);
    finalize_rowptr<<<(NN + TB - 1) / TB, blk, 0, stream>>>(cnt, bsums, row_ptr, NN);
    fill_kernel<<<grid_e, blk, 0, stream>>>(edges, E, row_ptr, cursor, col_src);

    // Layer 1 (K=32, relu)
    aggregate32<<<grid_n32, blk, 0, stream>>>(x, row_ptr, col_src, aggr, NN);
    gemm_mfma<32, true, false><<<grid_g, blk, 0, stream>>>(
        aggr, x, W1l_hi, W1l_lo, W1r_hi, W1r_lo, b1, hA, nullptr);

    // Layer 2 (K=128, relu)
    aggregate128<<<grid_n64, blk, 0, stream>>>(hA, row_ptr, col_src, aggr, NN);
    gemm_mfma<128, true, false><<<grid_g, blk, 0, stream>>>(
        aggr, hA, W2l_hi, W2l_lo, W2r_hi, W2r_lo, b2, hB, nullptr);

    // Layer 3 (K=128, no relu, fused column-mean into gsum)
    aggregate128<<<grid_n64, blk, 0, stream>>>(hB, row_ptr, col_src, aggr, NN);
    gemm_mfma<128, false, true><<<grid_g, blk, 0, stream>>>(
        aggr, hB, W3l_hi, W3l_lo, W3r_hi, W3r_lo, b3, nullptr, gsum);

    // Heads
    heads_kernel<<<1, 256, 0, stream>>>(gsum, Pw1, Pb1, Pw2, Pb2,
                                        Vw1, Vb1, Vw2, Vb2, outp,
                                        1.0f / (float)NN);
}

// Round 4
// 671.984 us; speedup vs baseline: 1.1391x; 1.1391x over previous
//
#include <hip/hip_runtime.h>
#include <hip/hip_bf16.h>

#define NN   100000
#define HIDD 128

typedef __attribute__((ext_vector_type(8))) short bf16x8;
typedef __attribute__((ext_vector_type(4))) float f32x4;

// RNE fp32 -> bf16 bits
__device__ __forceinline__ short bf16_rne(float v) {
    unsigned u = __float_as_uint(v);
    unsigned r = (u + 0x7fffu + ((u >> 16) & 1u)) >> 16;
    return (short)r;
}
__device__ __forceinline__ float bf16_to_f32(short b) {
    return __uint_as_float(((unsigned)(unsigned short)b) << 16);
}

// ---------------------------------------------------------------------------
// CSR build
// ---------------------------------------------------------------------------
__global__ void count_kernel(const int* __restrict__ edges, int n_edges,
                             int* __restrict__ cnt) {
    int e = blockIdx.x * blockDim.x + threadIdx.x;
    if (e >= n_edges) return;
    unsigned s = (unsigned)edges[e];
    unsigned d = (unsigned)edges[n_edges + e];
    if (s < NN && d < NN) atomicAdd(&cnt[d], 1);
}

__global__ __launch_bounds__(256)
void scan_blocks(const int* __restrict__ cnt, int* __restrict__ partial,
                 int* __restrict__ bsums, int n) {
    __shared__ int lds[256];
    int t = threadIdx.x;
    int base = blockIdx.x * 1024 + t * 4;
    int v0 = 0, v1 = 0, v2 = 0, v3 = 0;
    if (base + 3 < n) {
        int4 v = *(const int4*)&cnt[base];
        v0 = v.x; v1 = v.y; v2 = v.z; v3 = v.w;
    } else {
        if (base + 0 < n) v0 = cnt[base + 0];
        if (base + 1 < n) v1 = cnt[base + 1];
        if (base + 2 < n) v2 = cnt[base + 2];
    }
    lds[t] = v0 + v1 + v2 + v3;
    __syncthreads();
    for (int off = 1; off < 256; off <<= 1) {
        int u = (t >= off) ? lds[t - off] : 0;
        __syncthreads();
        lds[t] += u;
        __syncthreads();
    }
    int excl = (t == 0) ? 0 : lds[t - 1];
    int i0 = excl + v0, i1 = i0 + v1, i2 = i1 + v2, i3 = i2 + v3;
    if (base + 0 < n) partial[base + 0] = i0;
    if (base + 1 < n) partial[base + 1] = i1;
    if (base + 2 < n) partial[base + 2] = i2;
    if (base + 3 < n) partial[base + 3] = i3;
    if (t == 255) bsums[blockIdx.x] = lds[255];
}

__global__ void scan_bsums(int* __restrict__ bsums, int nb) {
    __shared__ int lds[128];
    int t = threadIdx.x;
    lds[t] = (t < nb) ? bsums[t] : 0;
    __syncthreads();
    for (int off = 1; off < 128; off <<= 1) {
        int u = (t >= off) ? lds[t - off] : 0;
        __syncthreads();
        lds[t] += u;
        __syncthreads();
    }
    if (t < nb) bsums[t] = lds[t];
}

__global__ void finalize_rowptr(const int* __restrict__ partial,
                                const int* __restrict__ bsums,
                                int* __restrict__ row_ptr, int n) {
    int i = blockIdx.x * blockDim.x + threadIdx.x;
    if (i < n) {
        int b = i >> 10;
        int off = (b > 0) ? bsums[b - 1] : 0;
        row_ptr[i + 1] = partial[i] + off;
    }
    if (i == 0) row_ptr[0] = 0;
}

__global__ void fill_kernel(const int* __restrict__ edges, int n_edges,
                            const int* __restrict__ row_ptr,
                            int* __restrict__ cursor, int* __restrict__ col_src) {
    int e = blockIdx.x * blockDim.x + threadIdx.x;
    if (e >= n_edges) return;
    unsigned s = (unsigned)edges[e];
    unsigned d = (unsigned)edges[n_edges + e];
    if (s < NN && d < NN) {
        int pos = atomicAdd(&cursor[d], 1);
        col_src[row_ptr[d] + pos] = (int)s;
    }
}

// ---------------------------------------------------------------------------
// Pull-mode mean aggregation (fp32 canonical activations)
// ---------------------------------------------------------------------------
__global__ void aggregate128(const float* __restrict__ h,
                             const int* __restrict__ row_ptr,
                             const int* __restrict__ col_src,
                             float* __restrict__ aggr, int n_nodes) {
    int node = (int)((blockIdx.x * (size_t)blockDim.x + threadIdx.x) >> 6);
    int lane = threadIdx.x & 63;
    if (node >= n_nodes) return;
    int beg = row_ptr[node], end = row_ptr[node + 1];
    float ax = 0.f, ay = 0.f;
    int j = beg;
    for (; j + 4 <= end; j += 4) {
        int s0 = col_src[j], s1 = col_src[j + 1];
        int s2 = col_src[j + 2], s3 = col_src[j + 3];
        float2 v0 = *(const float2*)&h[(size_t)s0 * HIDD + lane * 2];
        float2 v1 = *(const float2*)&h[(size_t)s1 * HIDD + lane * 2];
        float2 v2 = *(const float2*)&h[(size_t)s2 * HIDD + lane * 2];
        float2 v3 = *(const float2*)&h[(size_t)s3 * HIDD + lane * 2];
        ax += (v0.x + v1.x) + (v2.x + v3.x);
        ay += (v0.y + v1.y) + (v2.y + v3.y);
    }
    for (; j < end; ++j) {
        int s = col_src[j];
        float2 v = *(const float2*)&h[(size_t)s * HIDD + lane * 2];
        ax += v.x; ay += v.y;
    }
    float inv = (end > beg) ? 1.0f / (float)(end - beg) : 0.0f;
    float2 o; o.x = ax * inv; o.y = ay * inv;
    *(float2*)&aggr[(size_t)node * HIDD + lane * 2] = o;
}

__global__ void aggregate32(const float* __restrict__ x,
                            const int* __restrict__ row_ptr,
                            const int* __restrict__ col_src,
                            float* __restrict__ aggr, int n_nodes) {
    int node = (int)((blockIdx.x * (size_t)blockDim.x + threadIdx.x) >> 5);
    int lane = threadIdx.x & 31;
    if (node >= n_nodes) return;
    int beg = row_ptr[node], end = row_ptr[node + 1];
    float a = 0.f;
    int j = beg;
    for (; j + 4 <= end; j += 4) {
        int s0 = col_src[j], s1 = col_src[j + 1];
        int s2 = col_src[j + 2], s3 = col_src[j + 3];
        float u0 = x[(size_t)s0 * 32 + lane];
        float u1 = x[(size_t)s1 * 32 + lane];
        float u2 = x[(size_t)s2 * 32 + lane];
        float u3 = x[(size_t)s3 * 32 + lane];
        a += (u0 + u1) + (u2 + u3);
    }
    for (; j < end; ++j) a += x[(size_t)col_src[j] * 32 + lane];
    float inv = (end > beg) ? 1.0f / (float)(end - beg) : 0.0f;
    aggr[(size_t)node * 32 + lane] = a * inv;
}

// ---------------------------------------------------------------------------
// Weight pre-split: fp32 -> (hi, lo) bf16 planes, all 6 conv matrices.
// ---------------------------------------------------------------------------
__global__ void split_weights(const float* __restrict__ W1l, const float* __restrict__ W1r,
                              const float* __restrict__ W2l, const float* __restrict__ W2r,
                              const float* __restrict__ W3l, const float* __restrict__ W3r,
                              short* __restrict__ whi, short* __restrict__ wlo) {
    int i = blockIdx.x * blockDim.x + threadIdx.x;
    if (i >= 73728) return;
    const float* src; int off;
    if (i < 4096)       { src = W1l; off = 0; }
    else if (i < 8192)  { src = W1r; off = 4096; }
    else if (i < 24576) { src = W2l; off = 8192; }
    else if (i < 40960) { src = W2r; off = 24576; }
    else if (i < 57344) { src = W3l; off = 40960; }
    else                { src = W3r; off = 57344; }
    float v = src[i - off];
    short h = bf16_rne(v);
    float l = v - bf16_to_f32(h);
    whi[i] = h;
    wlo[i] = bf16_rne(l);
}

// ---------------------------------------------------------------------------
// MFMA dual GEMM, split-bf16 precision (Ahi*Whi + Ahi*Wlo + Alo*Whi).
// Block = 256 thr = 4 waves; block tile 64 rows x 128 cols.
// Wave: 32 rows (2 row-tiles) x 64 cols (4 col-tiles of 16).
// Per k-chunk(32): 4 A loads + 8 W loads issued as independent batches
// (deep MLP), then 24 MFMA. W-fragment loads amortized over 2 row-tiles.
// Tail: row index clamped for loads; stores/MEAN guarded by row < NN.
// MEAN: column sums (no bias) accumulated into gsum; bias folded in heads.
// ---------------------------------------------------------------------------
template <int KA, bool RELU, bool MEAN>
__global__ __launch_bounds__(256)
void gemm_mfma(const float* __restrict__ inA, const float* __restrict__ inB,
               const short* __restrict__ WAhi, const short* __restrict__ WAlo,
               const short* __restrict__ WBhi, const short* __restrict__ WBlo,
               const float* __restrict__ bias,
               float* __restrict__ out, float* __restrict__ gsum) {
    __shared__ float gl[128];
    const int t = threadIdx.x;
    const int wave = t >> 6, lane = t & 63;
    const int lrow = lane & 15;
    const int lk8  = (lane >> 4) * 8;
    const int n0 = blockIdx.x * 64 + (wave >> 1) * 32;   // wave's 32-row base
    const int o0 = (wave & 1) * 64;                      // wave's 64-col base

    if (MEAN) {
        if (t < 128) gl[t] = 0.f;
        __syncthreads();
    }

    // clamped row indices for the 2 row-tiles (loads only)
    int rowIdx0 = min(n0 + 0  + lrow, NN - 1);
    int rowIdx1 = min(n0 + 16 + lrow, NN - 1);

    f32x4 acc[2][4];
#pragma unroll
    for (int rt = 0; rt < 2; ++rt)
#pragma unroll
        for (int c = 0; c < 4; ++c) acc[rt][c] = (f32x4){0.f, 0.f, 0.f, 0.f};

    for (int op = 0; op < 2; ++op) {
        const float* __restrict__ in  = op ? inB : inA;
        const short* __restrict__ Whi = op ? WBhi : WAhi;
        const short* __restrict__ Wlo = op ? WBlo : WAlo;
        const float* a0base = in + (size_t)rowIdx0 * KA + lk8;
        const float* a1base = in + (size_t)rowIdx1 * KA + lk8;
#pragma unroll
        for (int k0 = 0; k0 < KA; k0 += 32) {
            // ---- issue all 12 loads up front (independent, deep MLP) ----
            float4 a00 = *(const float4*)(a0base + k0);
            float4 a01 = *(const float4*)(a0base + k0 + 4);
            float4 a10 = *(const float4*)(a1base + k0);
            float4 a11 = *(const float4*)(a1base + k0 + 4);
            bf16x8 wh[4], wl[4];
#pragma unroll
            for (int ct = 0; ct < 4; ++ct) {
                size_t wbase = (size_t)(o0 + ct * 16 + lrow) * KA + k0 + lk8;
                wh[ct] = *(const bf16x8*)&Whi[wbase];
                wl[ct] = *(const bf16x8*)&Wlo[wbase];
            }
            // ---- split A to hi/lo bf16 ----
            float av0[8] = {a00.x, a00.y, a00.z, a00.w, a01.x, a01.y, a01.z, a01.w};
            float av1[8] = {a10.x, a10.y, a10.z, a10.w, a11.x, a11.y, a11.z, a11.w};
            bf16x8 ahi0, alo0, ahi1, alo1;
#pragma unroll
            for (int e = 0; e < 8; ++e) {
                short h0 = bf16_rne(av0[e]);
                ahi0[e] = h0;
                alo0[e] = bf16_rne(av0[e] - bf16_to_f32(h0));
                short h1 = bf16_rne(av1[e]);
                ahi1[e] = h1;
                alo1[e] = bf16_rne(av1[e] - bf16_to_f32(h1));
            }
            // ---- 24 MFMA ----
#pragma unroll
            for (int ct = 0; ct < 4; ++ct) {
                acc[0][ct] = __builtin_amdgcn_mfma_f32_16x16x32_bf16(ahi0, wh[ct], acc[0][ct], 0, 0, 0);
                acc[0][ct] = __builtin_amdgcn_mfma_f32_16x16x32_bf16(ahi0, wl[ct], acc[0][ct], 0, 0, 0);
                acc[0][ct] = __builtin_amdgcn_mfma_f32_16x16x32_bf16(alo0, wh[ct], acc[0][ct], 0, 0, 0);
                acc[1][ct] = __builtin_amdgcn_mfma_f32_16x16x32_bf16(ahi1, wh[ct], acc[1][ct], 0, 0, 0);
                acc[1][ct] = __builtin_amdgcn_mfma_f32_16x16x32_bf16(ahi1, wl[ct], acc[1][ct], 0, 0, 0);
                acc[1][ct] = __builtin_amdgcn_mfma_f32_16x16x32_bf16(alo1, wh[ct], acc[1][ct], 0, 0, 0);
            }
        }
    }

    const int rg = (lane >> 4) * 4;  // row group base within a 16-row tile
    if (!MEAN) {
#pragma unroll
        for (int rt = 0; rt < 2; ++rt) {
#pragma unroll
            for (int ct = 0; ct < 4; ++ct) {
                int o = o0 + ct * 16 + lrow;
                float b = bias[o];
#pragma unroll
                for (int r = 0; r < 4; ++r) {
                    int row = n0 + rt * 16 + rg + r;
                    if (row < NN) {
                        float v = acc[rt][ct][r] + b;
                        if (RELU) v = fmaxf(v, 0.f);
                        out[(size_t)row * HIDD + o] = v;
                    }
                }
            }
        }
    } else {
#pragma unroll
        for (int ct = 0; ct < 4; ++ct) {
            float s = 0.f;
#pragma unroll
            for (int rt = 0; rt < 2; ++rt) {
#pragma unroll
                for (int r = 0; r < 4; ++r) {
                    int row = n0 + rt * 16 + rg + r;
                    if (row < NN) s += acc[rt][ct][r];
                }
            }
            s += __shfl_xor(s, 16);
            s += __shfl_xor(s, 32);
            if (lane < 16) atomicAdd(&gl[o0 + ct * 16 + lane], s);
        }
        __syncthreads();
        if (t < 128) atomicAdd(&gsum[t], gl[t]);
    }
}

// ---------------------------------------------------------------------------
// Heads: g = gsum/N + b3; logits = relu(g@Pw1.T+Pb1)@Pw2.T+Pb2; value likewise.
// ---------------------------------------------------------------------------
__global__ void heads_kernel(const float* __restrict__ gsum,
                             const float* __restrict__ b3,
                             const float* __restrict__ Pw1, const float* __restrict__ Pb1,
                             const float* __restrict__ Pw2, const float* __restrict__ Pb2,
                             const float* __restrict__ Vw1, const float* __restrict__ Vb1,
                             const float* __restrict__ Vw2, const float* __restrict__ Vb2,
                             float* __restrict__ out, float inv_n) {
    __shared__ float g[128], a1[128], v1[128];
    int t = threadIdx.x;
    if (t < 128) g[t] = gsum[t] * inv_n + b3[t];
    __syncthreads();
    if (t < 128) {
        float s = Pb1[t];
        for (int f = 0; f < 128; ++f) s = fmaf(Pw1[t * 128 + f], g[f], s);
        a1[t] = fmaxf(s, 0.f);
    } else {
        int o = t - 128;
        float s = Vb1[o];
        for (int f = 0; f < 128; ++f) s = fmaf(Vw1[o * 128 + f], g[f], s);
        v1[o] = fmaxf(s, 0.f);
    }
    __syncthreads();
    if (t < 6) {
        float s = Pb2[t];
        for (int f = 0; f < 128; ++f) s = fmaf(Pw2[t * 128 + f], a1[f], s);
        out[t] = s;
    }
    if (t == 6) {
        float s = Vb2[0];
        for (int f = 0; f < 128; ++f) s = fmaf(Vw2[f], v1[f], s);
        out[6] = s;
    }
}

// ---------------------------------------------------------------------------
extern "C" void kernel_launch(void* const* d_in, const int* in_sizes, int n_in,
                              void* d_out, int out_size, void* d_ws, size_t ws_size,
                              hipStream_t stream) {
    const float* x    = (const float*)d_in[0];
    const int*   edges = (const int*)d_in[1];
    const float* W1l = (const float*)d_in[2];
    const float* b1  = (const float*)d_in[3];
    const float* W1r = (const float*)d_in[4];
    const float* W2l = (const float*)d_in[5];
    const float* b2  = (const float*)d_in[6];
    const float* W2r = (const float*)d_in[7];
    const float* W3l = (const float*)d_in[8];
    const float* b3  = (const float*)d_in[9];
    const float* W3r = (const float*)d_in[10];
    const float* Pw1 = (const float*)d_in[11];
    const float* Pb1 = (const float*)d_in[12];
    const float* Pw2 = (const float*)d_in[13];
    const float* Pb2 = (const float*)d_in[14];
    const float* Vw1 = (const float*)d_in[15];
    const float* Vb1 = (const float*)d_in[16];
    const float* Vw2 = (const float*)d_in[17];
    const float* Vb2 = (const float*)d_in[18];
    float* outp = (float*)d_out;

    const int E = in_sizes[1] / 2;

    // ---- workspace layout (4-byte element offsets) ----
    int*   ws_i = (int*)d_ws;
    float* ws_f = (float*)d_ws;
    size_t o_cnt    = 0;
    size_t o_cursor = NN;
    size_t o_gsum   = 2 * (size_t)NN;
    size_t o_bsums  = 2 * (size_t)NN + 128;
    size_t o_rowptr = 2 * (size_t)NN + 256;
    size_t o_col    = o_rowptr + ((NN + 1 + 63) / 64) * 64;
    size_t o_whi    = ((o_col + (size_t)E + 63) / 64) * 64;   // 73728 shorts = 36864 ints
    size_t o_wlo    = o_whi + 36864;
    size_t o_aggr   = o_wlo + 36864;
    size_t o_hA     = o_aggr + (size_t)NN * HIDD;
    size_t o_hB     = o_hA + (size_t)NN * HIDD;

    int*   cnt     = ws_i + o_cnt;
    int*   cursor  = ws_i + o_cursor;
    float* gsum    = ws_f + o_gsum;
    int*   bsums   = ws_i + o_bsums;
    int*   row_ptr = ws_i + o_rowptr;
    int*   col_src = ws_i + o_col;
    short* whi     = (short*)(ws_i + o_whi);
    short* wlo     = (short*)(ws_i + o_wlo);
    float* aggr    = ws_f + o_aggr;
    float* hA      = ws_f + o_hA;
    float* hB      = ws_f + o_hB;

    short* W1l_hi = whi + 0;     short* W1l_lo = wlo + 0;
    short* W1r_hi = whi + 4096;  short* W1r_lo = wlo + 4096;
    short* W2l_hi = whi + 8192;  short* W2l_lo = wlo + 8192;
    short* W2r_hi = whi + 24576; short* W2r_lo = wlo + 24576;
    short* W3l_hi = whi + 40960; short* W3l_lo = wlo + 40960;
    short* W3r_hi = whi + 57344; short* W3r_lo = wlo + 57344;

    hipMemsetAsync(d_ws, 0, (2 * (size_t)NN + 128) * sizeof(int), stream);

    const int TB = 256;
    dim3 blk(TB);
    dim3 grid_e((E + TB - 1) / TB);
    dim3 grid_n64(((size_t)NN * 64 + TB - 1) / TB);
    dim3 grid_n32(((size_t)NN * 32 + TB - 1) / TB);
    dim3 grid_g((NN + 63) / 64);             // 1563 blocks (64 rows each)

    split_weights<<<(73728 + TB - 1) / TB, blk, 0, stream>>>(
        W1l, W1r, W2l, W2r, W3l, W3r, whi, wlo);

    count_kernel<<<grid_e, blk, 0, stream>>>(edges, E, cnt);
    const int nb_scan = (NN + 1023) / 1024;
    scan_blocks<<<nb_scan, blk, 0, stream>>>(cnt, cnt /*alias ok*/, bsums, NN);
    scan_bsums<<<1, 128, 0, stream>>>(bsums, nb_scan);
    finalize_rowptr<<<(NN + TB - 1) / TB, blk, 0, stream>>>(cnt, bsums, row_ptr, NN);
    fill_kernel<<<grid_e, blk, 0, stream>>>(edges, E, row_ptr, cursor, col_src);

    // Layer 1 (K=32, relu)
    aggregate32<<<grid_n32, blk, 0, stream>>>(x, row_ptr, col_src, aggr, NN);
    gemm_mfma<32, true, false><<<grid_g, blk, 0, stream>>>(
        aggr, x, W1l_hi, W1l_lo, W1r_hi, W1r_lo, b1, hA, nullptr);

    // Layer 2 (K=128, relu)
    aggregate128<<<grid_n64, blk, 0, stream>>>(hA, row_ptr, col_src, aggr, NN);
    gemm_mfma<128, true, false><<<grid_g, blk, 0, stream>>>(
        aggr, hA, W2l_hi, W2l_lo, W2r_hi, W2r_lo, b2, hB, nullptr);

    // Layer 3 (K=128, no relu, fused column-mean into gsum)
    aggregate128<<<grid_n64, blk, 0, stream>>>(hB, row_ptr, col_src, aggr, NN);
    gemm_mfma<128, false, true><<<grid_g, blk, 0, stream>>>(
        aggr, hB, W3l_hi, W3l_lo, W3r_hi, W3r_lo, b3, nullptr, gsum);

    // Heads (bias b3 folded into global mean here)
    heads_kernel<<<1, 256, 0, stream>>>(gsum, b3, Pw1, Pb1, Pw2, Pb2,
                                        Vw1, Vb1, Vw2, Vb2, outp,
                                        1.0f / (float)NN);
}

// Round 6
// 429.785 us; speedup vs baseline: 1.7811x; 1.5635x over previous
//
#include <hip/hip_runtime.h>
#include <hip/hip_bf16.h>

#define NN   100000
#define HIDD 128
#define NB   782          // ceil(NN/128) buckets of 128 nodes

typedef __attribute__((ext_vector_type(8))) short bf16x8;
typedef __attribute__((ext_vector_type(4))) float f32x4;

// RNE fp32 -> bf16 bits
__device__ __forceinline__ short bf16_rne(float v) {
    unsigned u = __float_as_uint(v);
    unsigned r = (u + 0x7fffu + ((u >> 16) & 1u)) >> 16;
    return (short)r;
}
__device__ __forceinline__ float bf16_to_f32(short b) {
    return __uint_as_float(((unsigned)(unsigned short)b) << 16);
}
__device__ __forceinline__ float2 unpack2(unsigned u) {
    float2 r;
    r.x = __uint_as_float((u & 0xFFFFu) << 16);
    r.y = __uint_as_float(u & 0xFFFF0000u);
    return r;
}
__device__ __forceinline__ unsigned pack2(float a, float b) {
    return ((unsigned)(unsigned short)bf16_rne(a)) |
           (((unsigned)(unsigned short)bf16_rne(b)) << 16);
}

// ---------------------------------------------------------------------------
// Bucketed CSR build. bucket = dst >> 7 (128 nodes per bucket).
// ---------------------------------------------------------------------------
__global__ __launch_bounds__(256)
void bucket_hist(const int* __restrict__ edges, int n_edges,
                 int* __restrict__ bcnt) {
    __shared__ int lh[NB];
    for (int i = threadIdx.x; i < NB; i += 256) lh[i] = 0;
    __syncthreads();
    int stride = gridDim.x * blockDim.x;
    for (int e = blockIdx.x * blockDim.x + threadIdx.x; e < n_edges; e += stride) {
        int d = edges[n_edges + e];
        if ((unsigned)d < NN) atomicAdd(&lh[d >> 7], 1);
    }
    __syncthreads();
    for (int i = threadIdx.x; i < NB; i += 256)
        if (lh[i]) atomicAdd(&bcnt[i], lh[i]);
}

__global__ void scan_bptr(const int* __restrict__ bcnt, int* __restrict__ bptr) {
    __shared__ int lds[1024];
    int t = threadIdx.x;
    lds[t] = (t < NB) ? bcnt[t] : 0;
    __syncthreads();
    for (int off = 1; off < 1024; off <<= 1) {
        int u = (t >= off) ? lds[t - off] : 0;
        __syncthreads();
        lds[t] += u;
        __syncthreads();
    }
    if (t < NB) bptr[t + 1] = lds[t];
    if (t == 0) bptr[0] = 0;
}

// Scatter edges into bucket regions as packed (dst_local<<17 | src).
// Per-block chunk reservation => dense runs per bucket => full-line writes.
#define SCAT_CHUNK 16384
__global__ __launch_bounds__(256)
void bucket_scatter(const int* __restrict__ edges, int n_edges,
                    const int* __restrict__ bptr, int* __restrict__ bcur,
                    int* __restrict__ bedges) {
    __shared__ int lh[NB];
    __shared__ int lbase[NB];
    int t = threadIdx.x;
    int base = blockIdx.x * SCAT_CHUNK;
    for (int i = t; i < NB; i += 256) lh[i] = 0;
    __syncthreads();
#pragma unroll 4
    for (int i = 0; i < SCAT_CHUNK / 256; ++i) {
        int e = base + i * 256 + t;
        if (e < n_edges) {
            int d = edges[n_edges + e];
            if ((unsigned)d < NN) atomicAdd(&lh[d >> 7], 1);
        }
    }
    __syncthreads();
    for (int i = t; i < NB; i += 256) {
        int c = lh[i];
        lbase[i] = (c > 0) ? atomicAdd(&bcur[i], c) : 0;
        lh[i] = 0;   // reuse as cursor
    }
    __syncthreads();
#pragma unroll 4
    for (int i = 0; i < SCAT_CHUNK / 256; ++i) {
        int e = base + i * 256 + t;
        if (e < n_edges) {
            int s = edges[e];
            int d = edges[n_edges + e];
            if ((unsigned)d < NN && (unsigned)s < NN) {
                int b = d >> 7;
                int off = atomicAdd(&lh[b], 1);
                bedges[bptr[b] + lbase[b] + off] = ((d & 127) << 17) | s;
            }
        }
    }
}

// One block per bucket: local count -> scan -> place. Emits row_ptr + col_src.
__global__ __launch_bounds__(256)
void bucket_csr(const int* __restrict__ bedges, const int* __restrict__ bptr,
                int* __restrict__ row_ptr, int* __restrict__ col_src) {
    __shared__ int lcnt[128];
    __shared__ int lexcl[128];
    int b = blockIdx.x;
    int t = threadIdx.x;
    int beg = bptr[b], end = bptr[b + 1];
    if (t < 128) lcnt[t] = 0;
    __syncthreads();
    for (int e = beg + t; e < end; e += 256)
        atomicAdd(&lcnt[bedges[e] >> 17], 1);
    __syncthreads();
    if (t < 128) lexcl[t] = lcnt[t];
    __syncthreads();
    for (int off = 1; off < 128; off <<= 1) {
        int u = (t < 128 && t >= off) ? lexcl[t - off] : 0;
        __syncthreads();
        if (t < 128) lexcl[t] += u;
        __syncthreads();
    }
    int node0 = b << 7;
    if (t < 128) {
        int excl = lexcl[t] - lcnt[t];   // exclusive scan
        int node = node0 + t;
        if (node < NN) row_ptr[node] = beg + excl;
        lexcl[t] = excl;
        lcnt[t] = 0;                     // reuse as cursor
    }
    if (b == NB - 1 && t == 0) row_ptr[NN] = end;
    __syncthreads();
    for (int e = beg + t; e < end; e += 256) {
        int p = bedges[e];
        int dl = p >> 17, src = p & 0x1FFFF;
        int pos = atomicAdd(&lcnt[dl], 1);
        col_src[beg + lexcl[dl] + pos] = src;
    }
}

// ---------------------------------------------------------------------------
// fp32 -> bf16 conversion (x)
// ---------------------------------------------------------------------------
__global__ void to_bf16(const float* __restrict__ in, ushort* __restrict__ out, int n) {
    int i = (blockIdx.x * blockDim.x + threadIdx.x) * 4;
    if (i + 3 >= n) {
        for (int k = i; k < n; ++k) out[k] = (ushort)bf16_rne(in[k]);
        return;
    }
    float4 v = *(const float4*)&in[i];
    unsigned lo = pack2(v.x, v.y), hi = pack2(v.z, v.w);
    *(uint2*)&out[i] = make_uint2(lo, hi);
}

// ---------------------------------------------------------------------------
// Pull-mode mean aggregation on bf16 activations.
// ---------------------------------------------------------------------------
__global__ void aggregate128_bf16(const ushort* __restrict__ h16,
                                  const int* __restrict__ row_ptr,
                                  const int* __restrict__ col_src,
                                  ushort* __restrict__ aggr16, int n_nodes) {
    int node = (int)((blockIdx.x * (size_t)blockDim.x + threadIdx.x) >> 6);
    int lane = threadIdx.x & 63;
    if (node >= n_nodes) return;
    int beg = row_ptr[node], end = row_ptr[node + 1];
    float ax = 0.f, ay = 0.f;
    int j = beg;
    for (; j + 4 <= end; j += 4) {
        int s0 = col_src[j],     s1 = col_src[j + 1];
        int s2 = col_src[j + 2], s3 = col_src[j + 3];
        unsigned u0 = *(const unsigned*)&h16[(size_t)s0 * HIDD + lane * 2];
        unsigned u1 = *(const unsigned*)&h16[(size_t)s1 * HIDD + lane * 2];
        unsigned u2 = *(const unsigned*)&h16[(size_t)s2 * HIDD + lane * 2];
        unsigned u3 = *(const unsigned*)&h16[(size_t)s3 * HIDD + lane * 2];
        float2 v0 = unpack2(u0), v1 = unpack2(u1), v2 = unpack2(u2), v3 = unpack2(u3);
        ax += (v0.x + v1.x) + (v2.x + v3.x);
        ay += (v0.y + v1.y) + (v2.y + v3.y);
    }
    for (; j < end; ++j) {
        float2 v = unpack2(*(const unsigned*)&h16[(size_t)col_src[j] * HIDD + lane * 2]);
        ax += v.x; ay += v.y;
    }
    float inv = (end > beg) ? 1.0f / (float)(end - beg) : 0.0f;
    *(unsigned*)&aggr16[(size_t)node * HIDD + lane * 2] = pack2(ax * inv, ay * inv);
}

// 16 lanes per node (K=32: 2 bf16 per lane)
__global__ void aggregate32_bf16(const ushort* __restrict__ x16,
                                 const int* __restrict__ row_ptr,
                                 const int* __restrict__ col_src,
                                 ushort* __restrict__ aggr16, int n_nodes) {
    int node = (int)((blockIdx.x * (size_t)blockDim.x + threadIdx.x) >> 4);
    int sl = threadIdx.x & 15;
    if (node >= n_nodes) return;
    int beg = row_ptr[node], end = row_ptr[node + 1];
    float ax = 0.f, ay = 0.f;
    int j = beg;
    for (; j + 4 <= end; j += 4) {
        int s0 = col_src[j],     s1 = col_src[j + 1];
        int s2 = col_src[j + 2], s3 = col_src[j + 3];
        float2 v0 = unpack2(*(const unsigned*)&x16[(size_t)s0 * 32 + sl * 2]);
        float2 v1 = unpack2(*(const unsigned*)&x16[(size_t)s1 * 32 + sl * 2]);
        float2 v2 = unpack2(*(const unsigned*)&x16[(size_t)s2 * 32 + sl * 2]);
        float2 v3 = unpack2(*(const unsigned*)&x16[(size_t)s3 * 32 + sl * 2]);
        ax += (v0.x + v1.x) + (v2.x + v3.x);
        ay += (v0.y + v1.y) + (v2.y + v3.y);
    }
    for (; j < end; ++j) {
        float2 v = unpack2(*(const unsigned*)&x16[(size_t)col_src[j] * 32 + sl * 2]);
        ax += v.x; ay += v.y;
    }
    float inv = (end > beg) ? 1.0f / (float)(end - beg) : 0.0f;
    *(unsigned*)&aggr16[(size_t)node * 32 + sl * 2] = pack2(ax * inv, ay * inv);
}

// ---------------------------------------------------------------------------
// Weight pre-split: fp32 -> (hi, lo) bf16 planes, all 6 conv matrices.
// ---------------------------------------------------------------------------
__global__ void split_weights(const float* __restrict__ W1l, const float* __restrict__ W1r,
                              const float* __restrict__ W2l, const float* __restrict__ W2r,
                              const float* __restrict__ W3l, const float* __restrict__ W3r,
                              short* __restrict__ whi, short* __restrict__ wlo) {
    int i = blockIdx.x * blockDim.x + threadIdx.x;
    if (i >= 73728) return;
    const float* src; int off;
    if (i < 4096)       { src = W1l; off = 0; }
    else if (i < 8192)  { src = W1r; off = 4096; }
    else if (i < 24576) { src = W2l; off = 8192; }
    else if (i < 40960) { src = W2r; off = 24576; }
    else if (i < 57344) { src = W3l; off = 40960; }
    else                { src = W3r; off = 57344; }
    float v = src[i - off];
    short h = bf16_rne(v);
    float l = v - bf16_to_f32(h);
    whi[i] = h;
    wlo[i] = bf16_rne(l);
}

// ---------------------------------------------------------------------------
// MFMA dual GEMM, bf16 activations + split-bf16 weights (A*Whi + A*Wlo).
// Block = 4 waves; tile 64 rows x 128 cols. Wave: 32 rows x 64 cols.
// Per k-chunk(32): 2 A loads + 8 W loads up front, then 16 MFMA.
// out stored bf16. MEAN: column sums into gsum (bias folded in heads).
// ---------------------------------------------------------------------------
template <int KA, bool RELU, bool MEAN>
__global__ __launch_bounds__(256)
void gemm_mfma(const ushort* __restrict__ inA, const ushort* __restrict__ inB,
               const short* __restrict__ WAhi, const short* __restrict__ WAlo,
               const short* __restrict__ WBhi, const short* __restrict__ WBlo,
               const float* __restrict__ bias,
               ushort* __restrict__ out, float* __restrict__ gsum) {
    __shared__ float gl[128];
    const int t = threadIdx.x;
    const int wave = t >> 6, lane = t & 63;
    const int lrow = lane & 15;
    const int lk8  = (lane >> 4) * 8;
    const int n0 = blockIdx.x * 64 + (wave >> 1) * 32;
    const int o0 = (wave & 1) * 64;

    if (MEAN) {
        if (t < 128) gl[t] = 0.f;
        __syncthreads();
    }

    int rowIdx0 = min(n0 + 0  + lrow, NN - 1);
    int rowIdx1 = min(n0 + 16 + lrow, NN - 1);

    f32x4 acc[2][4];
#pragma unroll
    for (int rt = 0; rt < 2; ++rt)
#pragma unroll
        for (int c = 0; c < 4; ++c) acc[rt][c] = (f32x4){0.f, 0.f, 0.f, 0.f};

    for (int op = 0; op < 2; ++op) {
        const ushort* __restrict__ in  = op ? inB : inA;
        const short* __restrict__ Whi = op ? WBhi : WAhi;
        const short* __restrict__ Wlo = op ? WBlo : WAlo;
        const ushort* a0base = in + (size_t)rowIdx0 * KA + lk8;
        const ushort* a1base = in + (size_t)rowIdx1 * KA + lk8;
#pragma unroll
        for (int k0 = 0; k0 < KA; k0 += 32) {
            bf16x8 a0 = *(const bf16x8*)(a0base + k0);
            bf16x8 a1 = *(const bf16x8*)(a1base + k0);
            bf16x8 wh[4], wl[4];
#pragma unroll
            for (int ct = 0; ct < 4; ++ct) {
                size_t wbase = (size_t)(o0 + ct * 16 + lrow) * KA + k0 + lk8;
                wh[ct] = *(const bf16x8*)&Whi[wbase];
                wl[ct] = *(const bf16x8*)&Wlo[wbase];
            }
#pragma unroll
            for (int ct = 0; ct < 4; ++ct) {
                acc[0][ct] = __builtin_amdgcn_mfma_f32_16x16x32_bf16(a0, wh[ct], acc[0][ct], 0, 0, 0);
                acc[0][ct] = __builtin_amdgcn_mfma_f32_16x16x32_bf16(a0, wl[ct], acc[0][ct], 0, 0, 0);
                acc[1][ct] = __builtin_amdgcn_mfma_f32_16x16x32_bf16(a1, wh[ct], acc[1][ct], 0, 0, 0);
                acc[1][ct] = __builtin_amdgcn_mfma_f32_16x16x32_bf16(a1, wl[ct], acc[1][ct], 0, 0, 0);
            }
        }
    }

    const int rg = (lane >> 4) * 4;
    if (!MEAN) {
#pragma unroll
        for (int rt = 0; rt < 2; ++rt) {
#pragma unroll
            for (int ct = 0; ct < 4; ++ct) {
                int o = o0 + ct * 16 + lrow;
                float b = bias[o];
#pragma unroll
                for (int r = 0; r < 4; ++r) {
                    int row = n0 + rt * 16 + rg + r;
                    if (row < NN) {
                        float v = acc[rt][ct][r] + b;
                        if (RELU) v = fmaxf(v, 0.f);
                        out[(size_t)row * HIDD + o] = (ushort)bf16_rne(v);
                    }
                }
            }
        }
    } else {
#pragma unroll
        for (int ct = 0; ct < 4; ++ct) {
            float s = 0.f;
#pragma unroll
            for (int rt = 0; rt < 2; ++rt)
#pragma unroll
                for (int r = 0; r < 4; ++r) {
                    int row = n0 + rt * 16 + rg + r;
                    if (row < NN) s += acc[rt][ct][r];
                }
            s += __shfl_xor(s, 16);
            s += __shfl_xor(s, 32);
            if (lane < 16) atomicAdd(&gl[o0 + ct * 16 + lane], s);
        }
        __syncthreads();
        if (t < 128) atomicAdd(&gsum[t], gl[t]);
    }
}

// ---------------------------------------------------------------------------
// Heads: g = gsum/N + b3; logits = relu(g@Pw1.T+Pb1)@Pw2.T+Pb2; value likewise.
// ---------------------------------------------------------------------------
__global__ void heads_kernel(const float* __restrict__ gsum,
                             const float* __restrict__ b3,
                             const float* __restrict__ Pw1, const float* __restrict__ Pb1,
                             const float* __restrict__ Pw2, const float* __restrict__ Pb2,
                             const float* __restrict__ Vw1, const float* __restrict__ Vb1,
                             const float* __restrict__ Vw2, const float* __restrict__ Vb2,
                             float* __restrict__ out, float inv_n) {
    __shared__ float g[128], a1[128], v1[128];
    int t = threadIdx.x;
    if (t < 128) g[t] = gsum[t] * inv_n + b3[t];
    __syncthreads();
    if (t < 128) {
        float s = Pb1[t];
        for (int f = 0; f < 128; ++f) s = fmaf(Pw1[t * 128 + f], g[f], s);
        a1[t] = fmaxf(s, 0.f);
    } else {
        int o = t - 128;
        float s = Vb1[o];
        for (int f = 0; f < 128; ++f) s = fmaf(Vw1[o * 128 + f], g[f], s);
        v1[o] = fmaxf(s, 0.f);
    }
    __syncthreads();
    if (t < 6) {
        float s = Pb2[t];
        for (int f = 0; f < 128; ++f) s = fmaf(Pw2[t * 128 + f], a1[f], s);
        out[t] = s;
    }
    if (t == 6) {
        float s = Vb2[0];
        for (int f = 0; f < 128; ++f) s = fmaf(Vw2[f], v1[f], s);
        out[6] = s;
    }
}

// ---------------------------------------------------------------------------
extern "C" void kernel_launch(void* const* d_in, const int* in_sizes, int n_in,
                              void* d_out, int out_size, void* d_ws, size_t ws_size,
                              hipStream_t stream) {
    const float* x    = (const float*)d_in[0];
    const int*   edges = (const int*)d_in[1];
    const float* W1l = (const float*)d_in[2];
    const float* b1  = (const float*)d_in[3];
    const float* W1r = (const float*)d_in[4];
    const float* W2l = (const float*)d_in[5];
    const float* b2  = (const float*)d_in[6];
    const float* W2r = (const float*)d_in[7];
    const float* W3l = (const float*)d_in[8];
    const float* b3  = (const float*)d_in[9];
    const float* W3r = (const float*)d_in[10];
    const float* Pw1 = (const float*)d_in[11];
    const float* Pb1 = (const float*)d_in[12];
    const float* Pw2 = (const float*)d_in[13];
    const float* Pb2 = (const float*)d_in[14];
    const float* Vw1 = (const float*)d_in[15];
    const float* Vb1 = (const float*)d_in[16];
    const float* Vw2 = (const float*)d_in[17];
    const float* Vb2 = (const float*)d_in[18];
    float* outp = (float*)d_out;

    const int E = in_sizes[1] / 2;

    // ---- workspace layout (int offsets, regions 256B-aligned) ----
    // whi/wlo are 73728 SHORTS = 36864 INTS each (r5 bug: used 18432 -> alias).
    int*   ws_i = (int*)d_ws;
    float* ws_f = (float*)d_ws;
    size_t o_bcnt = 0;                 // NB ints   (zeroed)
    size_t o_bcur = 832;               // NB ints   (zeroed)
    size_t o_gsum = 1664;              // 128 f32   (zeroed)
    size_t o_bptr = 1792;              // NB+1
    size_t o_rowp = 2624;              // NN+1
    size_t o_bed  = 102656;            // E packed bucket edges
    size_t o_col  = o_bed + (size_t)E;           // E
    size_t o_whi  = ((o_col + (size_t)E + 63) / 64) * 64;  // 73728 shorts = 36864 ints
    size_t o_wlo  = o_whi + 36864;
    size_t o_x16  = o_wlo + 36864;               // NN*32 bf16 = NN*16 ints
    size_t o_aggr = o_x16 + (size_t)NN * 16;     // NN*128 bf16 = NN*64 ints
    size_t o_hA   = o_aggr + (size_t)NN * 64;
    size_t o_hB   = o_hA + (size_t)NN * 64;

    int*    bcnt    = ws_i + o_bcnt;
    int*    bcur    = ws_i + o_bcur;
    float*  gsum    = ws_f + o_gsum;
    int*    bptr    = ws_i + o_bptr;
    int*    row_ptr = ws_i + o_rowp;
    int*    bedges  = ws_i + o_bed;
    int*    col_src = ws_i + o_col;
    short*  whi     = (short*)(ws_i + o_whi);
    short*  wlo     = (short*)(ws_i + o_wlo);
    ushort* x16     = (ushort*)(ws_i + o_x16);
    ushort* aggr    = (ushort*)(ws_i + o_aggr);
    ushort* hA      = (ushort*)(ws_i + o_hA);
    ushort* hB      = (ushort*)(ws_i + o_hB);

    short* W1l_hi = whi + 0;     short* W1l_lo = wlo + 0;
    short* W1r_hi = whi + 4096;  short* W1r_lo = wlo + 4096;
    short* W2l_hi = whi + 8192;  short* W2l_lo = wlo + 8192;
    short* W2r_hi = whi + 24576; short* W2r_lo = wlo + 24576;
    short* W3l_hi = whi + 40960; short* W3l_lo = wlo + 40960;
    short* W3r_hi = whi + 57344; short* W3r_lo = wlo + 57344;

    // zero bcnt, bcur, gsum
    hipMemsetAsync(d_ws, 0, 1792 * sizeof(int), stream);

    const int TB = 256;
    dim3 blk(TB);

    // independent prep
    to_bf16<<<(NN * 32 / 4 + TB - 1) / TB, blk, 0, stream>>>(x, x16, NN * 32);
    split_weights<<<(73728 + TB - 1) / TB, blk, 0, stream>>>(
        W1l, W1r, W2l, W2r, W3l, W3r, whi, wlo);

    // bucketed CSR build
    bucket_hist<<<256, blk, 0, stream>>>(edges, E, bcnt);
    scan_bptr<<<1, 1024, 0, stream>>>(bcnt, bptr);
    bucket_scatter<<<(E + SCAT_CHUNK - 1) / SCAT_CHUNK, blk, 0, stream>>>(
        edges, E, bptr, bcur, bedges);
    bucket_csr<<<NB, blk, 0, stream>>>(bedges, bptr, row_ptr, col_src);

    dim3 grid_a32((size_t)NN * 16 / TB);   // 6250
    dim3 grid_a128((size_t)NN * 64 / TB);  // 25000
    dim3 grid_g((NN + 63) / 64);           // 1563

    // Layer 1 (K=32, relu)
    aggregate32_bf16<<<grid_a32, blk, 0, stream>>>(x16, row_ptr, col_src, aggr, NN);
    gemm_mfma<32, true, false><<<grid_g, blk, 0, stream>>>(
        aggr, x16, W1l_hi, W1l_lo, W1r_hi, W1r_lo, b1, hA, nullptr);

    // Layer 2 (K=128, relu)
    aggregate128_bf16<<<grid_a128, blk, 0, stream>>>(hA, row_ptr, col_src, aggr, NN);
    gemm_mfma<128, true, false><<<grid_g, blk, 0, stream>>>(
        aggr, hA, W2l_hi, W2l_lo, W2r_hi, W2r_lo, b2, hB, nullptr);

    // Layer 3 (K=128, fused column-mean into gsum)
    aggregate128_bf16<<<grid_a128, blk, 0, stream>>>(hB, row_ptr, col_src, aggr, NN);
    gemm_mfma<128, false, true><<<grid_g, blk, 0, stream>>>(
        aggr, hB, W3l_hi, W3l_lo, W3r_hi, W3r_lo, b3, nullptr, gsum);

    // Heads (b3 folded into global mean here)
    heads_kernel<<<1, 256, 0, stream>>>(gsum, b3, Pw1, Pb1, Pw2, Pb2,
                                        Vw1, Vb1, Vw2, Vb2, outp,
                                        1.0f / (float)NN);
}

// Round 7
// 370.638 us; speedup vs baseline: 2.0653x; 1.1596x over previous
//
#include <hip/hip_runtime.h>
#include <hip/hip_bf16.h>

#define NN   100000
#define HIDD 128
#define NB   782          // ceil(NN/128) buckets of 128 nodes

typedef __attribute__((ext_vector_type(8))) short bf16x8;
typedef __attribute__((ext_vector_type(4))) float f32x4;

// RNE fp32 -> bf16 bits
__device__ __forceinline__ short bf16_rne(float v) {
    unsigned u = __float_as_uint(v);
    unsigned r = (u + 0x7fffu + ((u >> 16) & 1u)) >> 16;
    return (short)r;
}
__device__ __forceinline__ float bf16_to_f32(short b) {
    return __uint_as_float(((unsigned)(unsigned short)b) << 16);
}
__device__ __forceinline__ float2 unpack2(unsigned u) {
    float2 r;
    r.x = __uint_as_float((u & 0xFFFFu) << 16);
    r.y = __uint_as_float(u & 0xFFFF0000u);
    return r;
}
__device__ __forceinline__ unsigned pack2(float a, float b) {
    return ((unsigned)(unsigned short)bf16_rne(a)) |
           (((unsigned)(unsigned short)bf16_rne(b)) << 16);
}

// ---------------------------------------------------------------------------
// Bucketed CSR build. bucket = dst >> 7 (128 nodes per bucket).
// ---------------------------------------------------------------------------
__global__ __launch_bounds__(256)
void bucket_hist(const int* __restrict__ edges, int n_edges,
                 int* __restrict__ bcnt) {
    __shared__ int lh[NB];
    for (int i = threadIdx.x; i < NB; i += 256) lh[i] = 0;
    __syncthreads();
    int stride = gridDim.x * blockDim.x;
    for (int e = blockIdx.x * blockDim.x + threadIdx.x; e < n_edges; e += stride) {
        int d = edges[n_edges + e];
        if ((unsigned)d < NN) atomicAdd(&lh[d >> 7], 1);
    }
    __syncthreads();
    for (int i = threadIdx.x; i < NB; i += 256)
        if (lh[i]) atomicAdd(&bcnt[i], lh[i]);
}

__global__ void scan_bptr(const int* __restrict__ bcnt, int* __restrict__ bptr) {
    __shared__ int lds[1024];
    int t = threadIdx.x;
    lds[t] = (t < NB) ? bcnt[t] : 0;
    __syncthreads();
    for (int off = 1; off < 1024; off <<= 1) {
        int u = (t >= off) ? lds[t - off] : 0;
        __syncthreads();
        lds[t] += u;
        __syncthreads();
    }
    if (t < NB) bptr[t + 1] = lds[t];
    if (t == 0) bptr[0] = 0;
}

// Scatter edges into bucket regions as packed (dst_local<<17 | src).
#define SCAT_CHUNK 16384
__global__ __launch_bounds__(256)
void bucket_scatter(const int* __restrict__ edges, int n_edges,
                    const int* __restrict__ bptr, int* __restrict__ bcur,
                    int* __restrict__ bedges) {
    __shared__ int lh[NB];
    __shared__ int lbase[NB];
    int t = threadIdx.x;
    int base = blockIdx.x * SCAT_CHUNK;
    for (int i = t; i < NB; i += 256) lh[i] = 0;
    __syncthreads();
#pragma unroll 4
    for (int i = 0; i < SCAT_CHUNK / 256; ++i) {
        int e = base + i * 256 + t;
        if (e < n_edges) {
            int d = edges[n_edges + e];
            if ((unsigned)d < NN) atomicAdd(&lh[d >> 7], 1);
        }
    }
    __syncthreads();
    for (int i = t; i < NB; i += 256) {
        int c = lh[i];
        lbase[i] = (c > 0) ? atomicAdd(&bcur[i], c) : 0;
        lh[i] = 0;   // reuse as cursor
    }
    __syncthreads();
#pragma unroll 4
    for (int i = 0; i < SCAT_CHUNK / 256; ++i) {
        int e = base + i * 256 + t;
        if (e < n_edges) {
            int s = edges[e];
            int d = edges[n_edges + e];
            if ((unsigned)d < NN && (unsigned)s < NN) {
                int b = d >> 7;
                int off = atomicAdd(&lh[b], 1);
                bedges[bptr[b] + lbase[b] + off] = ((d & 127) << 17) | s;
            }
        }
    }
}

// One block per bucket: local count -> scan -> place. Emits row_ptr + col_src.
__global__ __launch_bounds__(256)
void bucket_csr(const int* __restrict__ bedges, const int* __restrict__ bptr,
                int* __restrict__ row_ptr, int* __restrict__ col_src) {
    __shared__ int lcnt[128];
    __shared__ int lexcl[128];
    int b = blockIdx.x;
    int t = threadIdx.x;
    int beg = bptr[b], end = bptr[b + 1];
    if (t < 128) lcnt[t] = 0;
    __syncthreads();
    for (int e = beg + t; e < end; e += 256)
        atomicAdd(&lcnt[bedges[e] >> 17], 1);
    __syncthreads();
    if (t < 128) lexcl[t] = lcnt[t];
    __syncthreads();
    for (int off = 1; off < 128; off <<= 1) {
        int u = (t < 128 && t >= off) ? lexcl[t - off] : 0;
        __syncthreads();
        if (t < 128) lexcl[t] += u;
        __syncthreads();
    }
    int node0 = b << 7;
    if (t < 128) {
        int excl = lexcl[t] - lcnt[t];   // exclusive scan
        int node = node0 + t;
        if (node < NN) row_ptr[node] = beg + excl;
        lexcl[t] = excl;
        lcnt[t] = 0;                     // reuse as cursor
    }
    if (b == NB - 1 && t == 0) row_ptr[NN] = end;
    __syncthreads();
    for (int e = beg + t; e < end; e += 256) {
        int p = bedges[e];
        int dl = p >> 17, src = p & 0x1FFFF;
        int pos = atomicAdd(&lcnt[dl], 1);
        col_src[beg + lexcl[dl] + pos] = src;
    }
}

// ---------------------------------------------------------------------------
// fp32 -> bf16 conversion (x)
// ---------------------------------------------------------------------------
__global__ void to_bf16(const float* __restrict__ in, ushort* __restrict__ out, int n) {
    int i = (blockIdx.x * blockDim.x + threadIdx.x) * 4;
    if (i + 3 >= n) {
        for (int k = i; k < n; ++k) out[k] = (ushort)bf16_rne(in[k]);
        return;
    }
    float4 v = *(const float4*)&in[i];
    unsigned lo = pack2(v.x, v.y), hi = pack2(v.z, v.w);
    *(uint2*)&out[i] = make_uint2(lo, hi);
}

// ---------------------------------------------------------------------------
// Pull-mode mean aggregation on bf16 activations (8-deep MLP unroll).
// ---------------------------------------------------------------------------
__global__ void aggregate128_bf16(const ushort* __restrict__ h16,
                                  const int* __restrict__ row_ptr,
                                  const int* __restrict__ col_src,
                                  ushort* __restrict__ aggr16, int n_nodes) {
    int node = (int)((blockIdx.x * (size_t)blockDim.x + threadIdx.x) >> 6);
    int lane = threadIdx.x & 63;
    if (node >= n_nodes) return;
    int beg = row_ptr[node], end = row_ptr[node + 1];
    float ax = 0.f, ay = 0.f;
    int j = beg;
    for (; j + 8 <= end; j += 8) {
        unsigned u0 = *(const unsigned*)&h16[(size_t)col_src[j + 0] * HIDD + lane * 2];
        unsigned u1 = *(const unsigned*)&h16[(size_t)col_src[j + 1] * HIDD + lane * 2];
        unsigned u2 = *(const unsigned*)&h16[(size_t)col_src[j + 2] * HIDD + lane * 2];
        unsigned u3 = *(const unsigned*)&h16[(size_t)col_src[j + 3] * HIDD + lane * 2];
        unsigned u4 = *(const unsigned*)&h16[(size_t)col_src[j + 4] * HIDD + lane * 2];
        unsigned u5 = *(const unsigned*)&h16[(size_t)col_src[j + 5] * HIDD + lane * 2];
        unsigned u6 = *(const unsigned*)&h16[(size_t)col_src[j + 6] * HIDD + lane * 2];
        unsigned u7 = *(const unsigned*)&h16[(size_t)col_src[j + 7] * HIDD + lane * 2];
        float2 v0 = unpack2(u0), v1 = unpack2(u1), v2 = unpack2(u2), v3 = unpack2(u3);
        float2 v4 = unpack2(u4), v5 = unpack2(u5), v6 = unpack2(u6), v7 = unpack2(u7);
        ax += ((v0.x + v1.x) + (v2.x + v3.x)) + ((v4.x + v5.x) + (v6.x + v7.x));
        ay += ((v0.y + v1.y) + (v2.y + v3.y)) + ((v4.y + v5.y) + (v6.y + v7.y));
    }
    for (; j + 4 <= end; j += 4) {
        unsigned u0 = *(const unsigned*)&h16[(size_t)col_src[j + 0] * HIDD + lane * 2];
        unsigned u1 = *(const unsigned*)&h16[(size_t)col_src[j + 1] * HIDD + lane * 2];
        unsigned u2 = *(const unsigned*)&h16[(size_t)col_src[j + 2] * HIDD + lane * 2];
        unsigned u3 = *(const unsigned*)&h16[(size_t)col_src[j + 3] * HIDD + lane * 2];
        float2 v0 = unpack2(u0), v1 = unpack2(u1), v2 = unpack2(u2), v3 = unpack2(u3);
        ax += (v0.x + v1.x) + (v2.x + v3.x);
        ay += (v0.y + v1.y) + (v2.y + v3.y);
    }
    for (; j < end; ++j) {
        float2 v = unpack2(*(const unsigned*)&h16[(size_t)col_src[j] * HIDD + lane * 2]);
        ax += v.x; ay += v.y;
    }
    float inv = (end > beg) ? 1.0f / (float)(end - beg) : 0.0f;
    *(unsigned*)&aggr16[(size_t)node * HIDD + lane * 2] = pack2(ax * inv, ay * inv);
}

// 16 lanes per node (K=32: 2 bf16 per lane)
__global__ void aggregate32_bf16(const ushort* __restrict__ x16,
                                 const int* __restrict__ row_ptr,
                                 const int* __restrict__ col_src,
                                 ushort* __restrict__ aggr16, int n_nodes) {
    int node = (int)((blockIdx.x * (size_t)blockDim.x + threadIdx.x) >> 4);
    int sl = threadIdx.x & 15;
    if (node >= n_nodes) return;
    int beg = row_ptr[node], end = row_ptr[node + 1];
    float ax = 0.f, ay = 0.f;
    int j = beg;
    for (; j + 8 <= end; j += 8) {
        float2 v0 = unpack2(*(const unsigned*)&x16[(size_t)col_src[j + 0] * 32 + sl * 2]);
        float2 v1 = unpack2(*(const unsigned*)&x16[(size_t)col_src[j + 1] * 32 + sl * 2]);
        float2 v2 = unpack2(*(const unsigned*)&x16[(size_t)col_src[j + 2] * 32 + sl * 2]);
        float2 v3 = unpack2(*(const unsigned*)&x16[(size_t)col_src[j + 3] * 32 + sl * 2]);
        float2 v4 = unpack2(*(const unsigned*)&x16[(size_t)col_src[j + 4] * 32 + sl * 2]);
        float2 v5 = unpack2(*(const unsigned*)&x16[(size_t)col_src[j + 5] * 32 + sl * 2]);
        float2 v6 = unpack2(*(const unsigned*)&x16[(size_t)col_src[j + 6] * 32 + sl * 2]);
        float2 v7 = unpack2(*(const unsigned*)&x16[(size_t)col_src[j + 7] * 32 + sl * 2]);
        ax += ((v0.x + v1.x) + (v2.x + v3.x)) + ((v4.x + v5.x) + (v6.x + v7.x));
        ay += ((v0.y + v1.y) + (v2.y + v3.y)) + ((v4.y + v5.y) + (v6.y + v7.y));
    }
    for (; j + 4 <= end; j += 4) {
        float2 v0 = unpack2(*(const unsigned*)&x16[(size_t)col_src[j + 0] * 32 + sl * 2]);
        float2 v1 = unpack2(*(const unsigned*)&x16[(size_t)col_src[j + 1] * 32 + sl * 2]);
        float2 v2 = unpack2(*(const unsigned*)&x16[(size_t)col_src[j + 2] * 32 + sl * 2]);
        float2 v3 = unpack2(*(const unsigned*)&x16[(size_t)col_src[j + 3] * 32 + sl * 2]);
        ax += (v0.x + v1.x) + (v2.x + v3.x);
        ay += (v0.y + v1.y) + (v2.y + v3.y);
    }
    for (; j < end; ++j) {
        float2 v = unpack2(*(const unsigned*)&x16[(size_t)col_src[j] * 32 + sl * 2]);
        ax += v.x; ay += v.y;
    }
    float inv = (end > beg) ? 1.0f / (float)(end - beg) : 0.0f;
    *(unsigned*)&aggr16[(size_t)node * 32 + sl * 2] = pack2(ax * inv, ay * inv);
}

// ---------------------------------------------------------------------------
// Weight pre-split: fp32 -> (hi, lo) bf16 planes, all 6 conv matrices.
// ---------------------------------------------------------------------------
__global__ void split_weights(const float* __restrict__ W1l, const float* __restrict__ W1r,
                              const float* __restrict__ W2l, const float* __restrict__ W2r,
                              const float* __restrict__ W3l, const float* __restrict__ W3r,
                              short* __restrict__ whi, short* __restrict__ wlo) {
    int i = blockIdx.x * blockDim.x + threadIdx.x;
    if (i >= 73728) return;
    const float* src; int off;
    if (i < 4096)       { src = W1l; off = 0; }
    else if (i < 8192)  { src = W1r; off = 4096; }
    else if (i < 24576) { src = W2l; off = 8192; }
    else if (i < 40960) { src = W2r; off = 24576; }
    else if (i < 57344) { src = W3l; off = 40960; }
    else                { src = W3r; off = 57344; }
    float v = src[i - off];
    short h = bf16_rne(v);
    float l = v - bf16_to_f32(h);
    whi[i] = h;
    wlo[i] = bf16_rne(l);
}

// ---------------------------------------------------------------------------
// Row-streaming MFMA dual GEMM with weights pinned in registers.
//   out[n][o] = maybe_relu( inA[n]@WA.T + inB[n]@WB.T + bias )
// Block = 4 waves; wave owns a fixed 32-col strip (2 col-tiles) and holds ALL
// its W fragments (hi+lo, both ops) in registers: KA=128 -> 32 x bf16x8.
// Block grid-strides over 16-row tiles (NN = 6250*16 exact, no tails).
// Per tile: 2*NCH A loads (prefetched one tile ahead, static indexing only)
// + 8*NCH MFMA. All 4 waves read the same A lines -> L1 hits.
// MEAN: per-wave column sums accumulated in registers across tiles; one
// shuffle-reduce + atomicAdd at kernel end. Bias folded in heads.
// ---------------------------------------------------------------------------
template <int KA, bool RELU, bool MEAN>
__global__ __launch_bounds__(256)
void gemm_mfma(const ushort* __restrict__ inA, const ushort* __restrict__ inB,
               const short* __restrict__ WAhi, const short* __restrict__ WAlo,
               const short* __restrict__ WBhi, const short* __restrict__ WBlo,
               const float* __restrict__ bias,
               ushort* __restrict__ out, float* __restrict__ gsum) {
    constexpr int NCH = KA / 32;        // k-chunks
    constexpr int NT  = NN / 16;        // 6250 row tiles
    const int t = threadIdx.x;
    const int wave = t >> 6, lane = t & 63;
    const int lrow = lane & 15;
    const int lk8  = (lane >> 4) * 8;
    const int o0   = wave * 32;         // wave's 32-col strip
    const int rg   = (lane >> 4) * 4;   // C row-group base

    // ---- W fragments into registers (whole kernel) ----
    bf16x8 w[2][NCH][2][2];             // [op][chunk][ct][plane]
#pragma unroll
    for (int op = 0; op < 2; ++op) {
        const short* __restrict__ Whi = op ? WBhi : WAhi;
        const short* __restrict__ Wlo = op ? WBlo : WAlo;
#pragma unroll
        for (int ch = 0; ch < NCH; ++ch)
#pragma unroll
            for (int ct = 0; ct < 2; ++ct) {
                size_t wb = (size_t)(o0 + ct * 16 + lrow) * KA + ch * 32 + lk8;
                w[op][ch][ct][0] = *(const bf16x8*)&Whi[wb];
                w[op][ch][ct][1] = *(const bf16x8*)&Wlo[wb];
            }
    }
    float bv[2];
#pragma unroll
    for (int ct = 0; ct < 2; ++ct) bv[ct] = MEAN ? 0.f : bias[o0 + ct * 16 + lrow];

    float csum[2] = {0.f, 0.f};

    const int stride = gridDim.x;
    int rt = blockIdx.x;

    // initial A load (tile rt)
    bf16x8 a[2][NCH];
#pragma unroll
    for (int op = 0; op < 2; ++op) {
        const ushort* __restrict__ in = op ? inB : inA;
        const ushort* ab = in + (size_t)(rt * 16 + lrow) * KA + lk8;
#pragma unroll
        for (int ch = 0; ch < NCH; ++ch) a[op][ch] = *(const bf16x8*)(ab + ch * 32);
    }

    while (rt < NT) {
        const int rtn = rt + stride;
        const int rtl = (rtn < NT) ? rtn : (NT - 1);   // clamped prefetch target
        // ---- prefetch next tile's A (independent of this tile's MFMAs) ----
        bf16x8 an[2][NCH];
#pragma unroll
        for (int op = 0; op < 2; ++op) {
            const ushort* __restrict__ in = op ? inB : inA;
            const ushort* ab = in + (size_t)(rtl * 16 + lrow) * KA + lk8;
#pragma unroll
            for (int ch = 0; ch < NCH; ++ch) an[op][ch] = *(const bf16x8*)(ab + ch * 32);
        }
        // ---- MFMA for current tile ----
        f32x4 acc[2];
#pragma unroll
        for (int ct = 0; ct < 2; ++ct) acc[ct] = (f32x4){0.f, 0.f, 0.f, 0.f};
#pragma unroll
        for (int op = 0; op < 2; ++op)
#pragma unroll
            for (int ch = 0; ch < NCH; ++ch)
#pragma unroll
                for (int ct = 0; ct < 2; ++ct) {
                    acc[ct] = __builtin_amdgcn_mfma_f32_16x16x32_bf16(a[op][ch], w[op][ch][ct][0], acc[ct], 0, 0, 0);
                    acc[ct] = __builtin_amdgcn_mfma_f32_16x16x32_bf16(a[op][ch], w[op][ch][ct][1], acc[ct], 0, 0, 0);
                }
        // ---- epilogue ----
        if (!MEAN) {
#pragma unroll
            for (int ct = 0; ct < 2; ++ct) {
                int o = o0 + ct * 16 + lrow;
#pragma unroll
                for (int r = 0; r < 4; ++r) {
                    float v = acc[ct][r] + bv[ct];
                    if (RELU) v = fmaxf(v, 0.f);
                    out[(size_t)(rt * 16 + rg + r) * HIDD + o] = (ushort)bf16_rne(v);
                }
            }
        } else {
#pragma unroll
            for (int ct = 0; ct < 2; ++ct)
                csum[ct] += (acc[ct][0] + acc[ct][1]) + (acc[ct][2] + acc[ct][3]);
        }
        // ---- rotate prefetch buffer (static indices) ----
#pragma unroll
        for (int op = 0; op < 2; ++op)
#pragma unroll
            for (int ch = 0; ch < NCH; ++ch) a[op][ch] = an[op][ch];
        rt = rtn;
    }

    if (MEAN) {
#pragma unroll
        for (int ct = 0; ct < 2; ++ct) {
            float s = csum[ct];
            s += __shfl_xor(s, 16);
            s += __shfl_xor(s, 32);
            if (lane < 16) atomicAdd(&gsum[o0 + ct * 16 + lane], s);
        }
    }
}

// ---------------------------------------------------------------------------
// Heads: g = gsum/N + b3; logits = relu(g@Pw1.T+Pb1)@Pw2.T+Pb2; value likewise.
// ---------------------------------------------------------------------------
__global__ void heads_kernel(const float* __restrict__ gsum,
                             const float* __restrict__ b3,
                             const float* __restrict__ Pw1, const float* __restrict__ Pb1,
                             const float* __restrict__ Pw2, const float* __restrict__ Pb2,
                             const float* __restrict__ Vw1, const float* __restrict__ Vb1,
                             const float* __restrict__ Vw2, const float* __restrict__ Vb2,
                             float* __restrict__ out, float inv_n) {
    __shared__ float g[128], a1[128], v1[128];
    int t = threadIdx.x;
    if (t < 128) g[t] = gsum[t] * inv_n + b3[t];
    __syncthreads();
    if (t < 128) {
        float s = Pb1[t];
        for (int f = 0; f < 128; ++f) s = fmaf(Pw1[t * 128 + f], g[f], s);
        a1[t] = fmaxf(s, 0.f);
    } else {
        int o = t - 128;
        float s = Vb1[o];
        for (int f = 0; f < 128; ++f) s = fmaf(Vw1[o * 128 + f], g[f], s);
        v1[o] = fmaxf(s, 0.f);
    }
    __syncthreads();
    if (t < 6) {
        float s = Pb2[t];
        for (int f = 0; f < 128; ++f) s = fmaf(Pw2[t * 128 + f], a1[f], s);
        out[t] = s;
    }
    if (t == 6) {
        float s = Vb2[0];
        for (int f = 0; f < 128; ++f) s = fmaf(Vw2[f], v1[f], s);
        out[6] = s;
    }
}

// ---------------------------------------------------------------------------
extern "C" void kernel_launch(void* const* d_in, const int* in_sizes, int n_in,
                              void* d_out, int out_size, void* d_ws, size_t ws_size,
                              hipStream_t stream) {
    const float* x    = (const float*)d_in[0];
    const int*   edges = (const int*)d_in[1];
    const float* W1l = (const float*)d_in[2];
    const float* b1  = (const float*)d_in[3];
    const float* W1r = (const float*)d_in[4];
    const float* W2l = (const float*)d_in[5];
    const float* b2  = (const float*)d_in[6];
    const float* W2r = (const float*)d_in[7];
    const float* W3l = (const float*)d_in[8];
    const float* b3  = (const float*)d_in[9];
    const float* W3r = (const float*)d_in[10];
    const float* Pw1 = (const float*)d_in[11];
    const float* Pb1 = (const float*)d_in[12];
    const float* Pw2 = (const float*)d_in[13];
    const float* Pb2 = (const float*)d_in[14];
    const float* Vw1 = (const float*)d_in[15];
    const float* Vb1 = (const float*)d_in[16];
    const float* Vw2 = (const float*)d_in[17];
    const float* Vb2 = (const float*)d_in[18];
    float* outp = (float*)d_out;

    const int E = in_sizes[1] / 2;

    // ---- workspace layout (int offsets, regions 256B-aligned) ----
    int*   ws_i = (int*)d_ws;
    float* ws_f = (float*)d_ws;
    size_t o_bcnt = 0;                 // NB ints   (zeroed)
    size_t o_bcur = 832;               // NB ints   (zeroed)
    size_t o_gsum = 1664;              // 128 f32   (zeroed)
    size_t o_bptr = 1792;              // NB+1
    size_t o_rowp = 2624;              // NN+1
    size_t o_bed  = 102656;            // E packed bucket edges
    size_t o_col  = o_bed + (size_t)E;           // E
    size_t o_whi  = ((o_col + (size_t)E + 63) / 64) * 64;  // 73728 shorts = 36864 ints
    size_t o_wlo  = o_whi + 36864;
    size_t o_x16  = o_wlo + 36864;               // NN*32 bf16 = NN*16 ints
    size_t o_aggr = o_x16 + (size_t)NN * 16;     // NN*128 bf16 = NN*64 ints
    size_t o_hA   = o_aggr + (size_t)NN * 64;
    size_t o_hB   = o_hA + (size_t)NN * 64;

    int*    bcnt    = ws_i + o_bcnt;
    int*    bcur    = ws_i + o_bcur;
    float*  gsum    = ws_f + o_gsum;
    int*    bptr    = ws_i + o_bptr;
    int*    row_ptr = ws_i + o_rowp;
    int*    bedges  = ws_i + o_bed;
    int*    col_src = ws_i + o_col;
    short*  whi     = (short*)(ws_i + o_whi);
    short*  wlo     = (short*)(ws_i + o_wlo);
    ushort* x16     = (ushort*)(ws_i + o_x16);
    ushort* aggr    = (ushort*)(ws_i + o_aggr);
    ushort* hA      = (ushort*)(ws_i + o_hA);
    ushort* hB      = (ushort*)(ws_i + o_hB);

    short* W1l_hi = whi + 0;     short* W1l_lo = wlo + 0;
    short* W1r_hi = whi + 4096;  short* W1r_lo = wlo + 4096;
    short* W2l_hi = whi + 8192;  short* W2l_lo = wlo + 8192;
    short* W2r_hi = whi + 24576; short* W2r_lo = wlo + 24576;
    short* W3l_hi = whi + 40960; short* W3l_lo = wlo + 40960;
    short* W3r_hi = whi + 57344; short* W3r_lo = wlo + 57344;

    // zero bcnt, bcur, gsum
    hipMemsetAsync(d_ws, 0, 1792 * sizeof(int), stream);

    const int TB = 256;
    dim3 blk(TB);

    // independent prep
    to_bf16<<<(NN * 32 / 4 + TB - 1) / TB, blk, 0, stream>>>(x, x16, NN * 32);
    split_weights<<<(73728 + TB - 1) / TB, blk, 0, stream>>>(
        W1l, W1r, W2l, W2r, W3l, W3r, whi, wlo);

    // bucketed CSR build
    bucket_hist<<<256, blk, 0, stream>>>(edges, E, bcnt);
    scan_bptr<<<1, 1024, 0, stream>>>(bcnt, bptr);
    bucket_scatter<<<(E + SCAT_CHUNK - 1) / SCAT_CHUNK, blk, 0, stream>>>(
        edges, E, bptr, bcur, bedges);
    bucket_csr<<<NB, blk, 0, stream>>>(bedges, bptr, row_ptr, col_src);

    dim3 grid_a32((size_t)NN * 16 / TB);   // 6250
    dim3 grid_a128((size_t)NN * 64 / TB);  // 25000
    dim3 grid_g(1250);                     // row-streaming GEMM: 5 tiles/block

    // Layer 1 (K=32, relu)
    aggregate32_bf16<<<grid_a32, blk, 0, stream>>>(x16, row_ptr, col_src, aggr, NN);
    gemm_mfma<32, true, false><<<grid_g, blk, 0, stream>>>(
        aggr, x16, W1l_hi, W1l_lo, W1r_hi, W1r_lo, b1, hA, nullptr);

    // Layer 2 (K=128, relu)
    aggregate128_bf16<<<grid_a128, blk, 0, stream>>>(hA, row_ptr, col_src, aggr, NN);
    gemm_mfma<128, true, false><<<grid_g, blk, 0, stream>>>(
        aggr, hA, W2l_hi, W2l_lo, W2r_hi, W2r_lo, b2, hB, nullptr);

    // Layer 3 (K=128, fused column-mean into gsum)
    aggregate128_bf16<<<grid_a128, blk, 0, stream>>>(hB, row_ptr, col_src, aggr, NN);
    gemm_mfma<128, false, true><<<grid_g, blk, 0, stream>>>(
        aggr, hB, W3l_hi, W3l_lo, W3r_hi, W3r_lo, b3, nullptr, gsum);

    // Heads (b3 folded into global mean here)
    heads_kernel<<<1, 256, 0, stream>>>(gsum, b3, Pw1, Pb1, Pw2, Pb2,
                                        Vw1, Vb1, Vw2, Vb2, outp,
                                        1.0f / (float)NN);
}